// Round 1
// baseline (572.145 us; speedup 1.0000x reference)
//
#include <hip/hip_runtime.h>

// x[2048,64,2] -> MLP(2->16 relu ->16) -> 8x LSTM(H=64) -> MLP(64->32 relu ->4)
// fp32 in/out. LSTM via split-bf16 MFMA (3-term, ~fp32 accuracy).
//
// Round 6: single-barrier step via gate-permuted weights + wave-local phase C.
//   grid 256 x 512 threads, M=8 batch rows/block (1 block/CU).
//   Weight permutation: wave wv's two n-tiles hold gates {i,f,g,o} for
//   j in [8wv, 8wv+8)  (tile0 cols 0..7=i, 8..15=f; tile1: g,o).
//   => phase C is wave-local: gates go through a per-wave LDS scratch
//   ([wave][gate*8+jj][m], b128 writes / 2-way-free b32 reads) with only a
//   lgkmcnt wait, NO s_barrier. One barrier per step (panel parity dbuf).
//   Split accumulators: 3 term-accs per n-tile -> 6 independent MFMA chains
//   of depth KT (was one 12-deep chain per tile).
//   Panel (x|h, bf16 hi/lo) parity double-buffered, LDP=136 (2-way-free b128).
//   x(t+1) register-prefetched (distance 2).

#define BATCH 2048
#define TT 64
#define HH 64
#define LDP 136   // panel row stride in shorts

typedef short bf16x8 __attribute__((ext_vector_type(8)));
typedef float f32x4 __attribute__((ext_vector_type(4)));

__device__ __forceinline__ float sigmoid_fast(float x) {
    // exp handles +-inf gracefully: rcp(inf)=0, rcp(1)=1 -> no clamp needed
    return __builtin_amdgcn_rcpf(1.f + __expf(-x));
}
__device__ __forceinline__ float tanh_fast(float x) {
    float e = __expf(-2.f * x);
    e = fminf(e, 1e30f);          // keep 1+e finite so rcp>0: tanh(-big) -> -1, not NaN
    return (1.f - e) * __builtin_amdgcn_rcpf(1.f + e);
}
__device__ __forceinline__ void split2(float x, unsigned short& hi, unsigned short& lo) {
    const unsigned u = __float_as_uint(x);
    hi = (unsigned short)(u >> 16);
    const float r = x - __uint_as_float(u & 0xFFFF0000u);  // exact
    lo = (unsigned short)(__float_as_uint(r) >> 16);
}

// ---------------- input MLP: 2 -> 16 relu -> 16 ----------------
__global__ __launch_bounds__(256)
void mlp_in_kernel(const float* __restrict__ x,
                   const float* __restrict__ w1, const float* __restrict__ b1,
                   const float* __restrict__ w2, const float* __restrict__ b2,
                   float* __restrict__ out) {
    const int gid = blockIdx.x * 256 + threadIdx.x;
    const float x0 = x[gid * 2 + 0];
    const float x1 = x[gid * 2 + 1];
    float hid[16];
#pragma unroll
    for (int j = 0; j < 16; ++j) {
        float v = fmaf(x1, w1[j * 2 + 1], fmaf(x0, w1[j * 2 + 0], b1[j]));
        hid[j] = fmaxf(0.f, v);
    }
    float o[16];
#pragma unroll
    for (int oo = 0; oo < 16; ++oo) {
        float acc = b2[oo];
#pragma unroll
        for (int j = 0; j < 16; ++j) acc = fmaf(hid[j], w2[oo * 16 + j], acc);
        o[oo] = acc;
    }
    float4* op = (float4*)(out + gid * 16);
#pragma unroll
    for (int q = 0; q < 4; ++q) {
        float4 v;
        v.x = o[q * 4 + 0]; v.y = o[q * 4 + 1]; v.z = o[q * 4 + 2]; v.w = o[q * 4 + 3];
        op[q] = v;
    }
}

// ---------------- LSTM layer, split-bf16 MFMA, M=8, 512 threads ----------------
// I = real input width; IPAD = padded x-region; K = IPAD + 64.
template <int I, int IPAD>
__global__ __launch_bounds__(512, 2)
void lstm_layer(const float* __restrict__ xin,
                const float* __restrict__ w_ih, const float* __restrict__ w_hh,
                const float* __restrict__ b_ih, const float* __restrict__ b_hh,
                float* __restrict__ hout) {
    constexpr int K = IPAD + 64;
    constexpr int KT = K / 32;
    __shared__ unsigned short ph[2][16 * LDP];  // parity panels, hi plane (rows 8..15 stay 0)
    __shared__ unsigned short pl[2][16 * LDP];  // lo plane
    __shared__ float gsw[8][32][8];             // per-wave gate scratch [wv][gate*8+jj][m]

    const int tid = threadIdx.x;
    const int wv = tid >> 6, lane = tid & 63, l16 = lane & 15, quad = lane >> 4;
    const int base = blockIdx.x * 8;

    for (int e = tid; e < 16 * LDP; e += 512) {
        ph[0][e] = 0; pl[0][e] = 0; ph[1][e] = 0; pl[1][e] = 0;
    }

    // --- weight B-fragments, GATE-PERMUTED ---
    // wave wv covers hidden units j in [8wv, 8wv+8).
    // tile ntl, col l16  ->  gate = ntl*2 + (l16>>3),  n = gate*64 + 8wv + (l16&7)
    bf16x8 bhi[KT][2], blo[KT][2];
    float bsum[2];
#pragma unroll
    for (int ntl = 0; ntl < 2; ++ntl) {
        const int gate = ntl * 2 + (l16 >> 3);
        const int n = gate * 64 + 8 * wv + (l16 & 7);
        bsum[ntl] = b_ih[n] + b_hh[n];
#pragma unroll
        for (int kt = 0; kt < KT; ++kt) {
#pragma unroll
            for (int j = 0; j < 8; ++j) {
                const int k = kt * 32 + quad * 8 + j;
                float w = 0.f;
                if (k < I) w = w_ih[n * I + k];
                else if (k >= IPAD) w = w_hh[n * 64 + (k - IPAD)];
                unsigned short h_, l_;
                split2(w, h_, l_);
                bhi[kt][ntl][j] = (short)h_;
                blo[kt][ntl][j] = (short)l_;
            }
        }
    }

    // phase-C slot: lane owns (m = lane>>3, j = 8wv + (lane&7)); c in one VGPR
    float c = 0.f;
    const int cm = lane >> 3, cjj = lane & 7;
    const int cj = 8 * wv + cjj;

    // staging: thread -> (row am, col ak)
    const int am = (I == 64) ? (tid >> 6) : (tid >> 4);
    const int ak = (I == 64) ? (tid & 63) : (tid & 15);
    const bool stg = (I == 64) ? true : (tid < 128);

    float xr = 0.f;
    if (stg) xr = xin[((size_t)(base + am) * TT + 0) * I + ak];
    if (stg) {
        unsigned short h_, l_;
        split2(xr, h_, l_);
        ph[0][am * LDP + ak] = h_;
        pl[0][am * LDP + ak] = l_;
    }
    if (stg) xr = xin[((size_t)(base + am) * TT + 1) * I + ak];
    __syncthreads();

    for (int t = 0; t < TT; ++t) {
        const int pb = t & 1;
        const unsigned short* php = ph[pb];
        const unsigned short* plp = pl[pb];
        unsigned short* phn = ph[pb ^ 1];
        unsigned short* pln = pl[pb ^ 1];

        // ---- phase B: gates = bias + [x|h] @ W^T, split accumulators ----
        // 6 independent MFMA chains of depth KT (a0=ahi*bhi(+bias), a1=alo*bhi, a2=ahi*blo)
        f32x4 a0[2], a1[2], a2[2];
#pragma unroll
        for (int ntl = 0; ntl < 2; ++ntl) {
            a0[ntl][0] = bsum[ntl]; a0[ntl][1] = bsum[ntl];
            a0[ntl][2] = bsum[ntl]; a0[ntl][3] = bsum[ntl];
            a1[ntl] = (f32x4){0.f, 0.f, 0.f, 0.f};
            a2[ntl] = (f32x4){0.f, 0.f, 0.f, 0.f};
        }
#pragma unroll
        for (int kt = 0; kt < KT; ++kt) {
            const int aoff = l16 * LDP + kt * 32 + quad * 8;
            const bf16x8 ahi = *(const bf16x8*)&php[aoff];
            const bf16x8 alo = *(const bf16x8*)&plp[aoff];
#pragma unroll
            for (int ntl = 0; ntl < 2; ++ntl) {
                a0[ntl] = __builtin_amdgcn_mfma_f32_16x16x32_bf16(ahi, bhi[kt][ntl], a0[ntl], 0, 0, 0);
                a1[ntl] = __builtin_amdgcn_mfma_f32_16x16x32_bf16(alo, bhi[kt][ntl], a1[ntl], 0, 0, 0);
                a2[ntl] = __builtin_amdgcn_mfma_f32_16x16x32_bf16(ahi, blo[kt][ntl], a2[ntl], 0, 0, 0);
            }
        }
        // D layout: row = quad*4+r (rows 0..7 real), col = l16.
        // Write this wave's gates to ITS OWN scratch region; consumed only in-wave,
        // so ordering is by lgkmcnt (compiler-inserted) -- NO barrier here.
        if (quad < 2) {
#pragma unroll
            for (int ntl = 0; ntl < 2; ++ntl) {
                const f32x4 s = (a0[ntl] + a1[ntl]) + a2[ntl];
                *(f32x4*)&gsw[wv][ntl * 16 + l16][quad * 4] = s;  // col*8+m layout, 16B aligned
            }
        }

        // ---- phase C: wave-local. lane (cm,cjj) reads its 4 gates ----
        const float gi = gsw[wv][0 * 8 + cjj][cm];
        const float gf = gsw[wv][1 * 8 + cjj][cm];
        const float gg = gsw[wv][2 * 8 + cjj][cm];
        const float go = gsw[wv][3 * 8 + cjj][cm];
        const float iv = sigmoid_fast(gi), fv = sigmoid_fast(gf);
        const float gv = tanh_fast(gg), ov = sigmoid_fast(go);
        c = fv * c + iv * gv;
        const float h = ov * tanh_fast(c);
        {
            unsigned short h_, l_;
            split2(h, h_, l_);
            phn[cm * LDP + IPAD + cj] = h_;
            pln[cm * LDP + IPAD + cj] = l_;
            hout[((size_t)(base + cm) * TT + t) * HH + cj] = h;
        }

        // ---- phase A: stage prefetched x(t+1) into next panel; prefetch x(t+2) ----
        if (stg) {
            unsigned short h_, l_;
            split2(xr, h_, l_);
            phn[am * LDP + ak] = h_;
            pln[am * LDP + ak] = l_;
            const int tp = (t + 2) & (TT - 1);
            xr = xin[((size_t)(base + am) * TT + tp) * I + ak];
        }
        __syncthreads();  // panel[pb^1] ready; also proves panel[pb] reads done
    }
}

// ---------------- output MLP: 64 -> 32 relu -> 4 ----------------
__global__ __launch_bounds__(256)
void mlp_out_kernel(const float* __restrict__ hin,
                    const float* __restrict__ wo1, const float* __restrict__ bo1,
                    const float* __restrict__ wo2, const float* __restrict__ bo2,
                    float* __restrict__ out) {
    __shared__ __align__(16) float wo1_s[32 * 64];
    __shared__ float bo1_s[32];
    __shared__ float wo2_s[4 * 32];
    __shared__ float bo2_s[4];
    const int tid = threadIdx.x;
    for (int e = tid; e < 32 * 64; e += 256) wo1_s[e] = wo1[e];
    if (tid < 32) bo1_s[tid] = bo1[tid];
    if (tid < 128) wo2_s[tid] = wo2[tid];
    if (tid < 4) bo2_s[tid] = bo2[tid];
    __syncthreads();

    const int gid = blockIdx.x * 256 + tid;
    const float4* hv = (const float4*)(hin + gid * 64);
    float4 h[16];
#pragma unroll
    for (int q = 0; q < 16; ++q) h[q] = hv[q];

    float m1[32];
#pragma unroll
    for (int o = 0; o < 32; ++o) {
        float acc = bo1_s[o];
        const float4* wrow = (const float4*)(wo1_s + o * 64);
#pragma unroll
        for (int q = 0; q < 16; ++q) {
            const float4 w = wrow[q];
            acc = fmaf(h[q].x, w.x, acc);
            acc = fmaf(h[q].y, w.y, acc);
            acc = fmaf(h[q].z, w.z, acc);
            acc = fmaf(h[q].w, w.w, acc);
        }
        m1[o] = fmaxf(0.f, acc);
    }
    float r[4];
#pragma unroll
    for (int q = 0; q < 4; ++q) {
        float acc = bo2_s[q];
#pragma unroll
        for (int o = 0; o < 32; ++o) acc = fmaf(m1[o], wo2_s[q * 32 + o], acc);
        r[q] = acc;
    }
    float4 res;
    res.x = r[0]; res.y = r[1]; res.z = r[2]; res.w = r[3];
    ((float4*)out)[gid] = res;
}

extern "C" void kernel_launch(void* const* d_in, const int* in_sizes, int n_in,
                              void* d_out, int out_size, void* d_ws, size_t ws_size,
                              hipStream_t stream) {
    const float* x     = (const float*)d_in[0];
    const float* w1    = (const float*)d_in[1];
    const float* b1    = (const float*)d_in[2];
    const float* w2    = (const float*)d_in[3];
    const float* b2    = (const float*)d_in[4];
    const float* w_ih0 = (const float*)d_in[5];
    const float* w_hh0 = (const float*)d_in[6];
    const float* b_ih0 = (const float*)d_in[7];
    const float* b_hh0 = (const float*)d_in[8];
    const float* w_ih  = (const float*)d_in[9];
    const float* w_hh  = (const float*)d_in[10];
    const float* b_ih  = (const float*)d_in[11];
    const float* b_hh  = (const float*)d_in[12];
    const float* wo1   = (const float*)d_in[13];
    const float* bo1   = (const float*)d_in[14];
    const float* wo2   = (const float*)d_in[15];
    const float* bo2   = (const float*)d_in[16];

    // workspace: buf_mlp B*T*16 | bufA B*T*64 | bufB B*T*64  (fp32)
    float* buf_mlp = (float*)d_ws;
    float* bufA = buf_mlp + (size_t)BATCH * TT * 16;
    float* bufB = bufA + (size_t)BATCH * TT * 64;

    const int nbt_blocks = (BATCH * TT) / 256;  // 512

    mlp_in_kernel<<<nbt_blocks, 256, 0, stream>>>(x, w1, b1, w2, b2, buf_mlp);

    lstm_layer<16, 32><<<BATCH / 8, 512, 0, stream>>>(buf_mlp, w_ih0, w_hh0, b_ih0, b_hh0, bufA);

    const float* cur = bufA;
    float* nxt = bufB;
    for (int l = 0; l < 7; ++l) {
        lstm_layer<64, 64><<<BATCH / 8, 512, 0, stream>>>(
            cur, w_ih + (size_t)l * 256 * 64, w_hh + (size_t)l * 256 * 64,
            b_ih + (size_t)l * 256, b_hh + (size_t)l * 256, nxt);
        const float* tmp = nxt;
        nxt = (float*)cur;
        cur = tmp;
    }

    mlp_out_kernel<<<nbt_blocks, 256, 0, stream>>>(cur, wo1, bo1, wo2, bo2, (float*)d_out);
}